// Round 15
// baseline (264.459 us; speedup 1.0000x reference)
//
#include <hip/hip_runtime.h>
#include <hip/hip_fp16.h>
#include <math.h>

#define N_NODES 100000
#define N_EDGES 1600000
#define EP (N_EDGES + N_NODES)   // edges incl self-loops
#define HID 64
#define NCHUNK 512                               // hist/scatter chunks
#define CE (N_EDGES / NCHUNK)                    // 3125 edges per chunk (exact)
#define NBUCK 782                                // buckets of 128 node-keys (99999>>7 = 781)
#define NHIST (NBUCK * NCHUNK)                   // 400384
#define NHB ((NHIST + 1023) / 1024)              // 392 scan blocks
#define NTILE (N_NODES / 16)                     // 6250 MFMA tiles (exact)
#define STASH 4096                               // per-bucket stash (u32); avg fill ~2046
#define OBSTRIDE 2048                            // u64 overflow slots per bucket
#define NPN 4                                    // nodes per wave (gather), even

typedef _Float16 half8_t __attribute__((ext_vector_type(8)));
typedef _Float16 half4_t __attribute__((ext_vector_type(4)));
typedef float f32x4_t __attribute__((ext_vector_type(4)));
typedef unsigned long long u64;

// ================= bucketed CSR build v4 (128-key buckets) =================

__global__ __launch_bounds__(256)
void hist_kernel(const int* __restrict__ dst, int* __restrict__ histA,
                 int* __restrict__ csr) {
    __shared__ int hist[NBUCK];
    const int tid = threadIdx.x, c = blockIdx.x;
    for (int b = tid; b < NBUCK; b += 256) hist[b] = 0;
    __syncthreads();
    for (int e = c * CE + tid; e < (c + 1) * CE; e += 256)
        atomicAdd(&hist[dst[e] >> 7], 1);
    __syncthreads();
    for (int b = tid; b < NBUCK; b += 256) histA[b * NCHUNK + c] = hist[b];
    if (c == 0 && tid < 64) csr[EP + tid] = 0;   // zero pad for gather over-read
}

__global__ void scang_block(const int* __restrict__ in, int* __restrict__ baseL,
                            int* __restrict__ bsum) {
    __shared__ int wsum[16];
    int tid = threadIdx.x, lane = tid & 63, wid = tid >> 6;
    int i = blockIdx.x * 1024 + tid;
    int x = (i < NHIST) ? in[i] : 0;
    int inc = x;
#pragma unroll
    for (int off = 1; off < 64; off <<= 1) {
        int y = __shfl_up(inc, off, 64);
        if (lane >= off) inc += y;
    }
    if (lane == 63) wsum[wid] = inc;
    __syncthreads();
    if (tid == 0) {
        int s = 0;
#pragma unroll
        for (int j = 0; j < 16; ++j) { int t2 = wsum[j]; wsum[j] = s; s += t2; }
    }
    __syncthreads();
    if (i < NHIST) baseL[i] = wsum[wid] + inc - x;
    if (tid == 1023) bsum[blockIdx.x] = wsum[15] + inc;
}

__global__ void scang_bsum(int* __restrict__ bsum) {   // NHB <= 512
    __shared__ int tmp[512];
    int t = threadIdx.x;
    tmp[t] = (t < NHB) ? bsum[t] : 0;
    __syncthreads();
    for (int off = 1; off < 512; off <<= 1) {
        int v = (t >= off) ? tmp[t - off] : 0;
        __syncthreads();
        tmp[t] += v;
        __syncthreads();
    }
    if (t < NHB) bsum[t] = (t == 0) ? 0 : tmp[t - 1];
}

__global__ __launch_bounds__(256)
void scatter_kernel(const int* __restrict__ src, const int* __restrict__ dst,
                    const int* __restrict__ baseL, const int* __restrict__ bsum,
                    unsigned* __restrict__ ebuf) {
    __shared__ int cur[NBUCK];
    const int tid = threadIdx.x, c = blockIdx.x;
    for (int b = tid; b < NBUCK; b += 256) {
        int idx = b * NCHUNK + c;
        cur[b] = baseL[idx] + bsum[idx >> 10];
    }
    __syncthreads();
    for (int e = c * CE + tid; e < (c + 1) * CE; e += 256) {
        int d = dst[e], s = src[e];
        int p = atomicAdd(&cur[d >> 7], 1);
        ebuf[p] = ((unsigned)(d & 127) << 17) | (unsigned)s;   // src < 2^17
    }
}

// rank + cnt scan -> rowptr/dinv/self-loop; csr fill. One block per 128-key bucket.

__global__ __launch_bounds__(256)
void rankfill_kernel(const unsigned* __restrict__ ebuf, const int* __restrict__ baseL,
                     const int* __restrict__ bsum, u64* __restrict__ obuf,
                     int* __restrict__ rowptr, int* __restrict__ csr,
                     float* __restrict__ dinv) {
    __shared__ int cnt[128];
    __shared__ int rpl[128];
    __shared__ int wsum[2];
    __shared__ int ocnt;
    __shared__ unsigned stash[STASH];
    const int tid = threadIdx.x, b = blockIdx.x;
    if (tid < 128) cnt[tid] = 0;
    if (tid == 0) ocnt = 0;
    __syncthreads();
    const int i0 = b * NCHUNK;
    const int R0 = baseL[i0] + bsum[i0 >> 10];
    const int i1 = (b + 1) * NCHUNK;
    const int R1 = (b == NBUCK - 1) ? N_EDGES : (baseL[i1] + bsum[i1 >> 10]);
    const int RL = R1 - R0;
    for (int off = tid; off < RL; off += 256) {
        unsigned v = ebuf[R0 + off];
        int key = (v >> 17) & 0x7F;
        int r = atomicAdd(&cnt[key], 1);
        if (off < STASH && r < 128) {
            stash[off] = ((unsigned)r << 25) | v;   // valid < 0xFFFFFFFF sentinel
        } else {
            if (off < STASH) stash[off] = 0xFFFFFFFFu;
            int oi = (off >= STASH) ? (off - STASH) : (1024 + atomicAdd(&ocnt, 1));
            obuf[(size_t)b * OBSTRIDE + oi] =
                ((u64)r << 40) | ((u64)key << 32) | (u64)(v & 0x1FFFFu);
        }
    }
    __syncthreads();
    // exclusive scan of cnt[128] (2 waves)
    const int lane = tid & 63;
    int x = 0, inc = 0;
    if (tid < 128) {
        x = cnt[tid];
        inc = x;
#pragma unroll
        for (int off = 1; off < 64; off <<= 1) {
            int y = __shfl_up(inc, off, 64);
            if (lane >= off) inc += y;
        }
        if (lane == 63) wsum[tid >> 6] = inc;
    }
    __syncthreads();
    if (tid < 128) {
        int base = (tid >= 64) ? wsum[0] : 0;
        int pre = base + inc - x;
        const int n = b * 128 + tid;
        const int rpn = R0 + n + pre;   // prev edges + prev self-loops + in-bucket prefix
        rpl[tid] = rpn;
        if (n < N_NODES) {
            rowptr[n] = rpn;
            dinv[n] = rsqrtf((float)(x + 1));
            csr[rpn + x] = n;           // self-loop at end of node's list
        }
        if (b == NBUCK - 1 && tid == 0) rowptr[N_NODES] = EP;
    }
    __syncthreads();
    const int lim = (RL < STASH) ? RL : STASH;
    for (int off = tid; off < lim; off += 256) {
        unsigned v = stash[off];
        if (v == 0xFFFFFFFFu) continue;
        csr[rpl[(v >> 17) & 0x7F] + (v >> 25)] = (int)(v & 0x1FFFFu);
    }
    for (int j = tid; j < RL - STASH; j += 256) {       // ≈ never
        u64 pk = obuf[(size_t)b * OBSTRIDE + j];
        csr[rpl[(pk >> 32) & 0x7F] + (int)(pk >> 40)] = (int)(pk & 0x1FFFFu);
    }
    for (int j = tid; j < ocnt; j += 256) {             // ≈ never
        u64 pk = obuf[(size_t)b * OBSTRIDE + 1024 + j];
        csr[rpl[(pk >> 32) & 0x7F] + (int)(pk >> 40)] = (int)(pk & 0x1FFFFu);
    }
}

// ---------------- layer 1: gf = fp16( dinv * (x @ W1) ), [N][64] ----------------

__global__ void layer1_kernel(const float* __restrict__ x, const float* __restrict__ W1,
                              const float* __restrict__ dinv, __half* __restrict__ gf) {
    int idx = blockIdx.x * blockDim.x + threadIdx.x;
    if (idx >= N_NODES * HID) return;
    int n = idx >> 6, c = idx & 63;
    float v = x[n * 3 + 0] * W1[c] + x[n * 3 + 1] * W1[HID + c]
            + x[n * 3 + 2] * W1[2 * HID + c];
    gf[idx] = __float2half(v * dinv[n]);
}

// ---------------- gather (R14-proven): 2-node pipeline + fused hv epilogue ----------------

__device__ __forceinline__ void addp(float4& a, uint2 u, bool pred) {
    __half2 h0 = *(__half2*)&u.x, h1 = *(__half2*)&u.y;
    float2 x = __half22float2(h0), y = __half22float2(h1);
    if (pred) { a.x += x.x; a.y += x.y; a.z += y.x; a.w += y.y; }
}

__device__ __forceinline__ void bfly_store(float4 acc, const float4 b4, float di,
                                           int g, int p, int n, __half* __restrict__ hv_out) {
    acc.x += __shfl_xor(acc.x, 16, 64);
    acc.y += __shfl_xor(acc.y, 16, 64);
    acc.z += __shfl_xor(acc.z, 16, 64);
    acc.w += __shfl_xor(acc.w, 16, 64);
    acc.x += __shfl_xor(acc.x, 32, 64);
    acc.y += __shfl_xor(acc.y, 32, 64);
    acc.z += __shfl_xor(acc.z, 32, 64);
    acc.w += __shfl_xor(acc.w, 32, 64);
    if (g == 0) {
        half4_t hv;
        hv[0] = (_Float16)fmaxf(fmaf(di, acc.x, b4.x), 0.f);
        hv[1] = (_Float16)fmaxf(fmaf(di, acc.y, b4.y), 0.f);
        hv[2] = (_Float16)fmaxf(fmaf(di, acc.z, b4.z), 0.f);
        hv[3] = (_Float16)fmaxf(fmaf(di, acc.w, b4.w), 0.f);
        *(half4_t*)(hv_out + (size_t)n * HID + p * 4) = hv;
    }
}

__global__ __launch_bounds__(256, 8)
void gather_kernel(const __half* __restrict__ gf, const int* __restrict__ rowptr,
                   const int* __restrict__ csr, const float* __restrict__ dinv,
                   const float* __restrict__ bias, __half* __restrict__ hv_out) {
    const int lane = threadIdx.x & 63, wid = threadIdx.x >> 6;
    const int g = lane >> 4, p = lane & 15;
    const int n0 = (blockIdx.x * 4 + wid) * NPN;
    int rp = rowptr[n0 + min(lane, NPN)];
    const uint2* gf2 = (const uint2*)gf;
    const float4 b4 = ((const float4*)bias)[p];
    int begv[NPN], cntv[NPN], idxv[NPN];
    int end_prev = __shfl(rp, 0, 64);
#pragma unroll
    for (int i = 0; i < NPN; ++i) {
        int end = __shfl(rp, i + 1, 64);
        begv[i] = end_prev;
        cntv[i] = end - end_prev;
        end_prev = end;
        idxv[i] = csr[begv[i] + lane];      // safe: csr padded by 64
    }
#pragma unroll
    for (int ii = 0; ii < NPN; ii += 2) {
        const int na = n0 + ii, nb = n0 + ii + 1;
        const int ca = cntv[ii], cb = cntv[ii + 1];
        const int ba = begv[ii], bb = begv[ii + 1];
        const int iva = idxv[ii], ivb = idxv[ii + 1];
        int sa0 = __shfl(iva, g, 64),      sb0 = __shfl(ivb, g, 64);
        int sa1 = __shfl(iva, g + 4, 64),  sb1 = __shfl(ivb, g + 4, 64);
        int sa2 = __shfl(iva, g + 8, 64),  sb2 = __shfl(ivb, g + 8, 64);
        int sa3 = __shfl(iva, g + 12, 64), sb3 = __shfl(ivb, g + 12, 64);
        uint2 ua0 = gf2[(size_t)sa0 * 16 + p], ub0 = gf2[(size_t)sb0 * 16 + p];
        uint2 ua1 = gf2[(size_t)sa1 * 16 + p], ub1 = gf2[(size_t)sb1 * 16 + p];
        uint2 ua2 = gf2[(size_t)sa2 * 16 + p], ub2 = gf2[(size_t)sb2 * 16 + p];
        uint2 ua3 = gf2[(size_t)sa3 * 16 + p], ub3 = gf2[(size_t)sb3 * 16 + p];
        float4 accA = make_float4(0.f, 0.f, 0.f, 0.f);
        float4 accB = make_float4(0.f, 0.f, 0.f, 0.f);
        addp(accA, ua0, g + 0 < ca);  addp(accB, ub0, g + 0 < cb);
        addp(accA, ua1, g + 4 < ca);  addp(accB, ub1, g + 4 < cb);
        addp(accA, ua2, g + 8 < ca);  addp(accB, ub2, g + 8 < cb);
        addp(accA, ua3, g + 12 < ca); addp(accB, ub3, g + 12 < cb);
        if (ca > 16) {
#pragma unroll
            for (int k = 4; k < 8; ++k) {
                int e = g + 4 * k;
                int s = __shfl(iva, e, 64);
                addp(accA, gf2[(size_t)s * 16 + p], e < ca);
            }
            if (ca > 32) {
                for (int e = 32 + g; e < ca; e += 4) {
                    int s = (e < 64) ? __shfl(iva, e, 64) : csr[ba + e];
                    addp(accA, gf2[(size_t)s * 16 + p], true);
                }
            }
        }
        if (cb > 16) {
#pragma unroll
            for (int k = 4; k < 8; ++k) {
                int e = g + 4 * k;
                int s = __shfl(ivb, e, 64);
                addp(accB, gf2[(size_t)s * 16 + p], e < cb);
            }
            if (cb > 32) {
                for (int e = 32 + g; e < cb; e += 4) {
                    int s = (e < 64) ? __shfl(ivb, e, 64) : csr[bb + e];
                    addp(accB, gf2[(size_t)s * 16 + p], true);
                }
            }
        }
        bfly_store(accA, b4, dinv[na], g, p, na, hv_out);
        bfly_store(accB, b4, dinv[nb], g, p, nb, hv_out);
    }
}

// ================= MFMA transform: gf_out = fp16( di * (hv @ W) ) =================

__global__ __launch_bounds__(256, 3)
void mfma_transform_kernel(const __half* __restrict__ hv_in, const float* __restrict__ dinv,
                           const float* __restrict__ W, __half* __restrict__ gf_out) {
    __shared__ __align__(16) _Float16 tile[4][16 * 72];
    const int lane = threadIdx.x & 63, wid = threadIdx.x >> 6;
    const int tid4 = blockIdx.x * 4 + wid;
    if (tid4 >= NTILE) return;
    const int n0 = tid4 * 16;
    _Float16* tl = &tile[wid][0];
    const int kg = lane >> 4, n = lane & 15;

    half8_t A0 = *(const half8_t*)(hv_in + (size_t)(n0 + n) * HID + kg * 8);
    half8_t A1 = *(const half8_t*)(hv_in + (size_t)(n0 + n) * HID + 32 + kg * 8);

    half8_t B[4][2];
#pragma unroll
    for (int t = 0; t < 4; ++t)
#pragma unroll
        for (int h = 0; h < 2; ++h)
#pragma unroll
            for (int j = 0; j < 8; ++j)
                B[t][h][j] = (_Float16)W[(h * 32 + kg * 8 + j) * HID + t * 16 + n];

    f32x4_t C[4];
#pragma unroll
    for (int t = 0; t < 4; ++t) {
        f32x4_t c = {0.f, 0.f, 0.f, 0.f};
        c = __builtin_amdgcn_mfma_f32_16x16x32_f16(A0, B[t][0], c, 0, 0, 0);
        c = __builtin_amdgcn_mfma_f32_16x16x32_f16(A1, B[t][1], c, 0, 0, 0);
        C[t] = c;
    }

    const int q = lane >> 4;
    float di4[4];
#pragma unroll
    for (int r = 0; r < 4; ++r) di4[r] = dinv[n0 + q * 4 + r];
#pragma unroll
    for (int t = 0; t < 4; ++t)
#pragma unroll
        for (int r = 0; r < 4; ++r)
            tl[(q * 4 + r) * 72 + t * 16 + n] = (_Float16)(C[t][r] * di4[r]);
    __builtin_amdgcn_s_waitcnt(0);
    const int r2 = lane >> 2, ch = lane & 3;
    uint4 v0 = *(const uint4*)(tl + r2 * 72 + ch * 16);
    uint4 v1 = *(const uint4*)(tl + r2 * 72 + ch * 16 + 8);
    *(uint4*)((__half*)gf_out + (size_t)(n0 + r2) * HID + ch * 16) = v0;
    *(uint4*)((__half*)gf_out + (size_t)(n0 + r2) * HID + ch * 16 + 8) = v1;
}

// ================= MFMA final: hv @ Wm1 + head + sigmoid (no LDS) =================

__global__ __launch_bounds__(256, 3)
void mfma_final_kernel(const __half* __restrict__ hv_in, const float* __restrict__ Wm1,
                       const float* __restrict__ bm1, const float* __restrict__ Wm2,
                       const float* __restrict__ bm2, float* __restrict__ out) {
    const int lane = threadIdx.x & 63, wid = threadIdx.x >> 6;
    const int tid4 = blockIdx.x * 4 + wid;
    if (tid4 >= NTILE) return;
    const int n0 = tid4 * 16;
    const int kg = lane >> 4, n = lane & 15;

    half8_t A0 = *(const half8_t*)(hv_in + (size_t)(n0 + n) * HID + kg * 8);
    half8_t A1 = *(const half8_t*)(hv_in + (size_t)(n0 + n) * HID + 32 + kg * 8);

    half8_t B[4][2];
#pragma unroll
    for (int t = 0; t < 4; ++t)
#pragma unroll
        for (int h = 0; h < 2; ++h)
#pragma unroll
            for (int j = 0; j < 8; ++j)
                B[t][h][j] = (_Float16)Wm1[(h * 32 + kg * 8 + j) * HID + t * 16 + n];

    f32x4_t C[4];
#pragma unroll
    for (int t = 0; t < 4; ++t) {
        f32x4_t c = {0.f, 0.f, 0.f, 0.f};
        c = __builtin_amdgcn_mfma_f32_16x16x32_f16(A0, B[t][0], c, 0, 0, 0);
        c = __builtin_amdgcn_mfma_f32_16x16x32_f16(A1, B[t][1], c, 0, 0, 0);
        C[t] = c;
    }

    float bm14[4], wm24[4];
#pragma unroll
    for (int t = 0; t < 4; ++t) { bm14[t] = bm1[t * 16 + n]; wm24[t] = Wm2[t * 16 + n]; }
    const float bm20 = bm2[0];
    float part[4] = {0.f, 0.f, 0.f, 0.f};
#pragma unroll
    for (int t = 0; t < 4; ++t)
#pragma unroll
        for (int r = 0; r < 4; ++r)
            part[r] += fmaxf(C[t][r] + bm14[t], 0.0f) * wm24[t];
#pragma unroll
    for (int off = 1; off < 16; off <<= 1)
#pragma unroll
        for (int r = 0; r < 4; ++r) part[r] += __shfl_xor(part[r], off, 64);
    if (n == 0) {
        const int q = lane >> 4;
#pragma unroll
        for (int r = 0; r < 4; ++r)
            out[n0 + q * 4 + r] = 1.0f / (1.0f + expf(-(part[r] + bm20)));
    }
}

// ---------------- launch ----------------

extern "C" void kernel_launch(void* const* d_in, const int* in_sizes, int n_in,
                              void* d_out, int out_size, void* d_ws, size_t ws_size,
                              hipStream_t stream) {
    const float* x   = (const float*)d_in[0];
    const int*   ei  = (const int*)d_in[1];
    const float* W1  = (const float*)d_in[2];
    const float* b1  = (const float*)d_in[3];
    const float* W2  = (const float*)d_in[4];
    const float* b2  = (const float*)d_in[5];
    const float* W3  = (const float*)d_in[6];
    const float* b3  = (const float*)d_in[7];
    const float* Wm1 = (const float*)d_in[8];
    const float* bm1 = (const float*)d_in[9];
    const float* Wm2 = (const float*)d_in[10];
    const float* bm2 = (const float*)d_in[11];
    float* out = (float*)d_out;

    const int* src = ei;
    const int* dst = ei + N_EDGES;

    char* ws = (char*)d_ws;
    size_t off = 0;
    auto alloc = [&](size_t bytes) { size_t o = off; off = (off + bytes + 255) & ~(size_t)255; return (void*)(ws + o); };
    int*      rowptr = (int*)alloc(4ll * (N_NODES + 1));
    int*      histA  = (int*)alloc(4ll * NHIST);
    int*      baseL  = (int*)alloc(4ll * NHIST);
    int*      bsum   = (int*)alloc(4ll * NHB);
    int*      csr    = (int*)alloc(4ll * (EP + 64));       // +64 pad (zeros)
    float*    dinv   = (float*)alloc(4ll * N_NODES);
    __half*   gfA    = (__half*)alloc(2ll * N_NODES * HID);
    __half*   gfB    = (__half*)alloc(2ll * N_NODES * HID);
    __half*   hvbuf  = (__half*)alloc(2ll * N_NODES * HID);
    unsigned* ebuf   = (unsigned*)alloc(4ll * N_EDGES);
    u64*      obuf   = (u64*)alloc(8ll * (size_t)NBUCK * OBSTRIDE);
    (void)ws_size;

    // --- CSR build v4: 5 dispatches, no memset, no global atomics ---
    hist_kernel<<<NCHUNK, 256, 0, stream>>>(dst, histA, csr);
    scang_block<<<NHB, 1024, 0, stream>>>(histA, baseL, bsum);
    scang_bsum<<<1, 512, 0, stream>>>(bsum);
    scatter_kernel<<<NCHUNK, 256, 0, stream>>>(src, dst, baseL, bsum, ebuf);
    rankfill_kernel<<<NBUCK, 256, 0, stream>>>(ebuf, baseL, bsum, obuf, rowptr, csr, dinv);

    // --- layers: gather(+hv) then MFMA transform ---
    const int gblocks = N_NODES / (4 * NPN);   // 6250, exact
    const int fblocks = (NTILE + 3) / 4;       // 1563
    layer1_kernel<<<(N_NODES * HID + 255) / 256, 256, 0, stream>>>(x, W1, dinv, gfA);
    gather_kernel<<<gblocks, 256, 0, stream>>>(gfA, rowptr, csr, dinv, b1, hvbuf);
    mfma_transform_kernel<<<fblocks, 256, 0, stream>>>(hvbuf, dinv, W2, gfB);
    gather_kernel<<<gblocks, 256, 0, stream>>>(gfB, rowptr, csr, dinv, b2, hvbuf);
    mfma_transform_kernel<<<fblocks, 256, 0, stream>>>(hvbuf, dinv, W3, gfA);
    gather_kernel<<<gblocks, 256, 0, stream>>>(gfA, rowptr, csr, dinv, b3, hvbuf);
    mfma_final_kernel<<<fblocks, 256, 0, stream>>>(hvbuf, Wm1, bm1, Wm2, bm2, out);
}

// Round 16
// 252.071 us; speedup vs baseline: 1.0491x; 1.0491x over previous
//
#include <hip/hip_runtime.h>
#include <hip/hip_fp16.h>
#include <math.h>

#define N_NODES 100000
#define N_EDGES 1600000
#define EP (N_EDGES + N_NODES)   // edges incl self-loops
#define HID 64
#define NCHUNK 128                               // hist/scatter chunks
#define CE (N_EDGES / NCHUNK)                    // 12500 edges per chunk (exact)
#define NBUCK 391                                // buckets of 256 node-keys
#define NHIST (NBUCK * NCHUNK)                   // 50048
#define NHB ((NHIST + 1023) / 1024)              // 49 scan blocks
#define NTILE (N_NODES / 16)                     // 6250 MFMA tiles (exact)
#define STASH 8192                               // per-bucket stash (u32); avg fill ~4092
#define OBSTRIDE 4096                            // u64 overflow slots per bucket
#define NPN 4                                    // nodes per wave (gather), even

typedef _Float16 half8_t __attribute__((ext_vector_type(8)));
typedef _Float16 half4_t __attribute__((ext_vector_type(4)));
typedef float f32x4_t __attribute__((ext_vector_type(4)));
typedef unsigned long long u64;

// ================= bucketed CSR build v5 (fewer, longer chunks; int4 loads) =================

__global__ __launch_bounds__(1024)
void hist_kernel(const int* __restrict__ dst, int* __restrict__ histA,
                 int* __restrict__ csr) {
    __shared__ int hist[NBUCK];
    const int tid = threadIdx.x, c = blockIdx.x;
    for (int b = tid; b < NBUCK; b += 1024) hist[b] = 0;
    __syncthreads();
    const int4* d4p = (const int4*)(dst + c * CE);
    for (int t = tid; t < CE / 4; t += 1024) {
        int4 d = d4p[t];
        atomicAdd(&hist[d.x >> 8], 1);
        atomicAdd(&hist[d.y >> 8], 1);
        atomicAdd(&hist[d.z >> 8], 1);
        atomicAdd(&hist[d.w >> 8], 1);
    }
    __syncthreads();
    for (int b = tid; b < NBUCK; b += 1024) histA[b * NCHUNK + c] = hist[b];
    if (c == 0 && tid < 64) csr[EP + tid] = 0;   // zero pad for gather over-read
}

__global__ void scang_block(const int* __restrict__ in, int* __restrict__ baseL,
                            int* __restrict__ bsum) {
    __shared__ int wsum[16];
    int tid = threadIdx.x, lane = tid & 63, wid = tid >> 6;
    int i = blockIdx.x * 1024 + tid;
    int x = (i < NHIST) ? in[i] : 0;
    int inc = x;
#pragma unroll
    for (int off = 1; off < 64; off <<= 1) {
        int y = __shfl_up(inc, off, 64);
        if (lane >= off) inc += y;
    }
    if (lane == 63) wsum[wid] = inc;
    __syncthreads();
    if (tid == 0) {
        int s = 0;
#pragma unroll
        for (int j = 0; j < 16; ++j) { int t2 = wsum[j]; wsum[j] = s; s += t2; }
    }
    __syncthreads();
    if (i < NHIST) baseL[i] = wsum[wid] + inc - x;
    if (tid == 1023) bsum[blockIdx.x] = wsum[15] + inc;
}

__global__ void scang_bsum(int* __restrict__ bsum) {   // NHB <= 256
    __shared__ int tmp[256];
    int t = threadIdx.x;
    tmp[t] = (t < NHB) ? bsum[t] : 0;
    __syncthreads();
    for (int off = 1; off < 256; off <<= 1) {
        int v = (t >= off) ? tmp[t - off] : 0;
        __syncthreads();
        tmp[t] += v;
        __syncthreads();
    }
    if (t < NHB) bsum[t] = (t == 0) ? 0 : tmp[t - 1];
}

__global__ __launch_bounds__(1024)
void scatter_kernel(const int* __restrict__ src, const int* __restrict__ dst,
                    const int* __restrict__ baseL, const int* __restrict__ bsum,
                    unsigned* __restrict__ ebuf) {
    __shared__ int cur[NBUCK];
    const int tid = threadIdx.x, c = blockIdx.x;
    for (int b = tid; b < NBUCK; b += 1024) {
        int idx = b * NCHUNK + c;
        cur[b] = baseL[idx] + bsum[idx >> 10];
    }
    __syncthreads();
    const int4* s4p = (const int4*)(src + c * CE);
    const int4* d4p = (const int4*)(dst + c * CE);
    for (int t = tid; t < CE / 4; t += 1024) {
        int4 s = s4p[t];
        int4 d = d4p[t];
        int p0 = atomicAdd(&cur[d.x >> 8], 1);
        ebuf[p0] = ((unsigned)(d.x & 255) << 17) | (unsigned)s.x;
        int p1 = atomicAdd(&cur[d.y >> 8], 1);
        ebuf[p1] = ((unsigned)(d.y & 255) << 17) | (unsigned)s.y;
        int p2 = atomicAdd(&cur[d.z >> 8], 1);
        ebuf[p2] = ((unsigned)(d.z & 255) << 17) | (unsigned)s.z;
        int p3 = atomicAdd(&cur[d.w >> 8], 1);
        ebuf[p3] = ((unsigned)(d.w & 255) << 17) | (unsigned)s.w;
    }
}

// rank + cnt scan -> rowptr/dinv/self-loop; csr fill. One block per 256-key bucket.

__global__ __launch_bounds__(256)
void rankfill_kernel(const unsigned* __restrict__ ebuf, const int* __restrict__ baseL,
                     const int* __restrict__ bsum, u64* __restrict__ obuf,
                     int* __restrict__ rowptr, int* __restrict__ csr,
                     float* __restrict__ dinv) {
    __shared__ int cnt[256];
    __shared__ int rpl[256];
    __shared__ int wsum[4];
    __shared__ int ocnt;
    __shared__ unsigned stash[STASH];
    const int tid = threadIdx.x, b = blockIdx.x;
    cnt[tid] = 0;
    if (tid == 0) ocnt = 0;
    __syncthreads();
    const int i0 = b * NCHUNK;
    const int R0 = baseL[i0] + bsum[i0 >> 10];
    const int i1 = (b + 1) * NCHUNK;
    const int R1 = (b == NBUCK - 1) ? N_EDGES : (baseL[i1] + bsum[i1 >> 10]);
    const int RL = R1 - R0;
    for (int off = tid; off < RL; off += 256) {
        unsigned v = ebuf[R0 + off];
        int key = (v >> 17) & 0xFF;
        int r = atomicAdd(&cnt[key], 1);
        if (off < STASH && r < 128) {
            stash[off] = ((unsigned)r << 25) | v;
        } else {
            if (off < STASH) stash[off] = 0xFFFFFFFFu;
            int oi = (off >= STASH) ? (off - STASH) : (2048 + atomicAdd(&ocnt, 1));
            obuf[(size_t)b * OBSTRIDE + oi] =
                ((u64)r << 40) | ((u64)key << 32) | (u64)(v & 0x1FFFFu);
        }
    }
    __syncthreads();
    const int lane = tid & 63, w = tid >> 6;
    int x = cnt[tid];
    int inc = x;
#pragma unroll
    for (int off = 1; off < 64; off <<= 1) {
        int y = __shfl_up(inc, off, 64);
        if (lane >= off) inc += y;
    }
    if (lane == 63) wsum[w] = inc;
    __syncthreads();
    int base = 0;
    for (int k = 0; k < 4; ++k) if (k < w) base += wsum[k];
    int pre = base + inc - x;
    const int n = b * 256 + tid;
    const int rpn = R0 + n + pre;
    rpl[tid] = rpn;
    if (n < N_NODES) {
        rowptr[n] = rpn;
        dinv[n] = rsqrtf((float)(x + 1));
        csr[rpn + x] = n;             // self-loop at end of node's list
    }
    if (b == NBUCK - 1 && tid == 0) rowptr[N_NODES] = EP;
    __syncthreads();
    const int lim = (RL < STASH) ? RL : STASH;
    for (int off = tid; off < lim; off += 256) {
        unsigned v = stash[off];
        if (v == 0xFFFFFFFFu) continue;
        csr[rpl[(v >> 17) & 0xFF] + (v >> 25)] = (int)(v & 0x1FFFFu);
    }
    for (int j = tid; j < RL - STASH; j += 256) {       // ≈ never
        u64 pk = obuf[(size_t)b * OBSTRIDE + j];
        csr[rpl[(pk >> 32) & 0xFF] + (int)(pk >> 40)] = (int)(pk & 0x1FFFFu);
    }
    for (int j = tid; j < ocnt; j += 256) {             // ≈ never
        u64 pk = obuf[(size_t)b * OBSTRIDE + 2048 + j];
        csr[rpl[(pk >> 32) & 0xFF] + (int)(pk >> 40)] = (int)(pk & 0x1FFFFu);
    }
}

// ---------------- layer 1: gf = fp16( dinv * (x @ W1) ), [N][64] ----------------

__global__ void layer1_kernel(const float* __restrict__ x, const float* __restrict__ W1,
                              const float* __restrict__ dinv, __half* __restrict__ gf) {
    int idx = blockIdx.x * blockDim.x + threadIdx.x;
    if (idx >= N_NODES * HID) return;
    int n = idx >> 6, c = idx & 63;
    float v = x[n * 3 + 0] * W1[c] + x[n * 3 + 1] * W1[HID + c]
            + x[n * 3 + 2] * W1[2 * HID + c];
    gf[idx] = __float2half(v * dinv[n]);
}

// ---------------- gather (R14-proven): 2-node pipeline + fused hv epilogue ----------------

__device__ __forceinline__ void addp(float4& a, uint2 u, bool pred) {
    __half2 h0 = *(__half2*)&u.x, h1 = *(__half2*)&u.y;
    float2 x = __half22float2(h0), y = __half22float2(h1);
    if (pred) { a.x += x.x; a.y += x.y; a.z += y.x; a.w += y.y; }
}

__device__ __forceinline__ void bfly_store(float4 acc, const float4 b4, float di,
                                           int g, int p, int n, __half* __restrict__ hv_out) {
    acc.x += __shfl_xor(acc.x, 16, 64);
    acc.y += __shfl_xor(acc.y, 16, 64);
    acc.z += __shfl_xor(acc.z, 16, 64);
    acc.w += __shfl_xor(acc.w, 16, 64);
    acc.x += __shfl_xor(acc.x, 32, 64);
    acc.y += __shfl_xor(acc.y, 32, 64);
    acc.z += __shfl_xor(acc.z, 32, 64);
    acc.w += __shfl_xor(acc.w, 32, 64);
    if (g == 0) {
        half4_t hv;
        hv[0] = (_Float16)fmaxf(fmaf(di, acc.x, b4.x), 0.f);
        hv[1] = (_Float16)fmaxf(fmaf(di, acc.y, b4.y), 0.f);
        hv[2] = (_Float16)fmaxf(fmaf(di, acc.z, b4.z), 0.f);
        hv[3] = (_Float16)fmaxf(fmaf(di, acc.w, b4.w), 0.f);
        *(half4_t*)(hv_out + (size_t)n * HID + p * 4) = hv;
    }
}

__global__ __launch_bounds__(256, 8)
void gather_kernel(const __half* __restrict__ gf, const int* __restrict__ rowptr,
                   const int* __restrict__ csr, const float* __restrict__ dinv,
                   const float* __restrict__ bias, __half* __restrict__ hv_out) {
    const int lane = threadIdx.x & 63, wid = threadIdx.x >> 6;
    const int g = lane >> 4, p = lane & 15;
    const int n0 = (blockIdx.x * 4 + wid) * NPN;
    int rp = rowptr[n0 + min(lane, NPN)];
    const uint2* gf2 = (const uint2*)gf;
    const float4 b4 = ((const float4*)bias)[p];
    int begv[NPN], cntv[NPN], idxv[NPN];
    int end_prev = __shfl(rp, 0, 64);
#pragma unroll
    for (int i = 0; i < NPN; ++i) {
        int end = __shfl(rp, i + 1, 64);
        begv[i] = end_prev;
        cntv[i] = end - end_prev;
        end_prev = end;
        idxv[i] = csr[begv[i] + lane];      // safe: csr padded by 64
    }
#pragma unroll
    for (int ii = 0; ii < NPN; ii += 2) {
        const int na = n0 + ii, nb = n0 + ii + 1;
        const int ca = cntv[ii], cb = cntv[ii + 1];
        const int ba = begv[ii], bb = begv[ii + 1];
        const int iva = idxv[ii], ivb = idxv[ii + 1];
        int sa0 = __shfl(iva, g, 64),      sb0 = __shfl(ivb, g, 64);
        int sa1 = __shfl(iva, g + 4, 64),  sb1 = __shfl(ivb, g + 4, 64);
        int sa2 = __shfl(iva, g + 8, 64),  sb2 = __shfl(ivb, g + 8, 64);
        int sa3 = __shfl(iva, g + 12, 64), sb3 = __shfl(ivb, g + 12, 64);
        uint2 ua0 = gf2[(size_t)sa0 * 16 + p], ub0 = gf2[(size_t)sb0 * 16 + p];
        uint2 ua1 = gf2[(size_t)sa1 * 16 + p], ub1 = gf2[(size_t)sb1 * 16 + p];
        uint2 ua2 = gf2[(size_t)sa2 * 16 + p], ub2 = gf2[(size_t)sb2 * 16 + p];
        uint2 ua3 = gf2[(size_t)sa3 * 16 + p], ub3 = gf2[(size_t)sb3 * 16 + p];
        float4 accA = make_float4(0.f, 0.f, 0.f, 0.f);
        float4 accB = make_float4(0.f, 0.f, 0.f, 0.f);
        addp(accA, ua0, g + 0 < ca);  addp(accB, ub0, g + 0 < cb);
        addp(accA, ua1, g + 4 < ca);  addp(accB, ub1, g + 4 < cb);
        addp(accA, ua2, g + 8 < ca);  addp(accB, ub2, g + 8 < cb);
        addp(accA, ua3, g + 12 < ca); addp(accB, ub3, g + 12 < cb);
        if (ca > 16) {
#pragma unroll
            for (int k = 4; k < 8; ++k) {
                int e = g + 4 * k;
                int s = __shfl(iva, e, 64);
                addp(accA, gf2[(size_t)s * 16 + p], e < ca);
            }
            if (ca > 32) {
                for (int e = 32 + g; e < ca; e += 4) {
                    int s = (e < 64) ? __shfl(iva, e, 64) : csr[ba + e];
                    addp(accA, gf2[(size_t)s * 16 + p], true);
                }
            }
        }
        if (cb > 16) {
#pragma unroll
            for (int k = 4; k < 8; ++k) {
                int e = g + 4 * k;
                int s = __shfl(ivb, e, 64);
                addp(accB, gf2[(size_t)s * 16 + p], e < cb);
            }
            if (cb > 32) {
                for (int e = 32 + g; e < cb; e += 4) {
                    int s = (e < 64) ? __shfl(ivb, e, 64) : csr[bb + e];
                    addp(accB, gf2[(size_t)s * 16 + p], true);
                }
            }
        }
        bfly_store(accA, b4, dinv[na], g, p, na, hv_out);
        bfly_store(accB, b4, dinv[nb], g, p, nb, hv_out);
    }
}

// ================= MFMA transform: gf_out = fp16( di * (hv @ W) ) =================

__global__ __launch_bounds__(256, 3)
void mfma_transform_kernel(const __half* __restrict__ hv_in, const float* __restrict__ dinv,
                           const float* __restrict__ W, __half* __restrict__ gf_out) {
    __shared__ __align__(16) _Float16 tile[4][16 * 72];
    const int lane = threadIdx.x & 63, wid = threadIdx.x >> 6;
    const int tid4 = blockIdx.x * 4 + wid;
    if (tid4 >= NTILE) return;
    const int n0 = tid4 * 16;
    _Float16* tl = &tile[wid][0];
    const int kg = lane >> 4, n = lane & 15;

    half8_t A0 = *(const half8_t*)(hv_in + (size_t)(n0 + n) * HID + kg * 8);
    half8_t A1 = *(const half8_t*)(hv_in + (size_t)(n0 + n) * HID + 32 + kg * 8);

    half8_t B[4][2];
#pragma unroll
    for (int t = 0; t < 4; ++t)
#pragma unroll
        for (int h = 0; h < 2; ++h)
#pragma unroll
            for (int j = 0; j < 8; ++j)
                B[t][h][j] = (_Float16)W[(h * 32 + kg * 8 + j) * HID + t * 16 + n];

    f32x4_t C[4];
#pragma unroll
    for (int t = 0; t < 4; ++t) {
        f32x4_t c = {0.f, 0.f, 0.f, 0.f};
        c = __builtin_amdgcn_mfma_f32_16x16x32_f16(A0, B[t][0], c, 0, 0, 0);
        c = __builtin_amdgcn_mfma_f32_16x16x32_f16(A1, B[t][1], c, 0, 0, 0);
        C[t] = c;
    }

    const int q = lane >> 4;
    float di4[4];
#pragma unroll
    for (int r = 0; r < 4; ++r) di4[r] = dinv[n0 + q * 4 + r];
#pragma unroll
    for (int t = 0; t < 4; ++t)
#pragma unroll
        for (int r = 0; r < 4; ++r)
            tl[(q * 4 + r) * 72 + t * 16 + n] = (_Float16)(C[t][r] * di4[r]);
    __builtin_amdgcn_s_waitcnt(0);
    const int r2 = lane >> 2, ch = lane & 3;
    uint4 v0 = *(const uint4*)(tl + r2 * 72 + ch * 16);
    uint4 v1 = *(const uint4*)(tl + r2 * 72 + ch * 16 + 8);
    *(uint4*)((__half*)gf_out + (size_t)(n0 + r2) * HID + ch * 16) = v0;
    *(uint4*)((__half*)gf_out + (size_t)(n0 + r2) * HID + ch * 16 + 8) = v1;
}

// ================= MFMA final: hv @ Wm1 + head + sigmoid (no LDS) =================

__global__ __launch_bounds__(256, 3)
void mfma_final_kernel(const __half* __restrict__ hv_in, const float* __restrict__ Wm1,
                       const float* __restrict__ bm1, const float* __restrict__ Wm2,
                       const float* __restrict__ bm2, float* __restrict__ out) {
    const int lane = threadIdx.x & 63, wid = threadIdx.x >> 6;
    const int tid4 = blockIdx.x * 4 + wid;
    if (tid4 >= NTILE) return;
    const int n0 = tid4 * 16;
    const int kg = lane >> 4, n = lane & 15;

    half8_t A0 = *(const half8_t*)(hv_in + (size_t)(n0 + n) * HID + kg * 8);
    half8_t A1 = *(const half8_t*)(hv_in + (size_t)(n0 + n) * HID + 32 + kg * 8);

    half8_t B[4][2];
#pragma unroll
    for (int t = 0; t < 4; ++t)
#pragma unroll
        for (int h = 0; h < 2; ++h)
#pragma unroll
            for (int j = 0; j < 8; ++j)
                B[t][h][j] = (_Float16)Wm1[(h * 32 + kg * 8 + j) * HID + t * 16 + n];

    f32x4_t C[4];
#pragma unroll
    for (int t = 0; t < 4; ++t) {
        f32x4_t c = {0.f, 0.f, 0.f, 0.f};
        c = __builtin_amdgcn_mfma_f32_16x16x32_f16(A0, B[t][0], c, 0, 0, 0);
        c = __builtin_amdgcn_mfma_f32_16x16x32_f16(A1, B[t][1], c, 0, 0, 0);
        C[t] = c;
    }

    float bm14[4], wm24[4];
#pragma unroll
    for (int t = 0; t < 4; ++t) { bm14[t] = bm1[t * 16 + n]; wm24[t] = Wm2[t * 16 + n]; }
    const float bm20 = bm2[0];
    float part[4] = {0.f, 0.f, 0.f, 0.f};
#pragma unroll
    for (int t = 0; t < 4; ++t)
#pragma unroll
        for (int r = 0; r < 4; ++r)
            part[r] += fmaxf(C[t][r] + bm14[t], 0.0f) * wm24[t];
#pragma unroll
    for (int off = 1; off < 16; off <<= 1)
#pragma unroll
        for (int r = 0; r < 4; ++r) part[r] += __shfl_xor(part[r], off, 64);
    if (n == 0) {
        const int q = lane >> 4;
#pragma unroll
        for (int r = 0; r < 4; ++r)
            out[n0 + q * 4 + r] = 1.0f / (1.0f + expf(-(part[r] + bm20)));
    }
}

// ---------------- launch ----------------

extern "C" void kernel_launch(void* const* d_in, const int* in_sizes, int n_in,
                              void* d_out, int out_size, void* d_ws, size_t ws_size,
                              hipStream_t stream) {
    const float* x   = (const float*)d_in[0];
    const int*   ei  = (const int*)d_in[1];
    const float* W1  = (const float*)d_in[2];
    const float* b1  = (const float*)d_in[3];
    const float* W2  = (const float*)d_in[4];
    const float* b2  = (const float*)d_in[5];
    const float* W3  = (const float*)d_in[6];
    const float* b3  = (const float*)d_in[7];
    const float* Wm1 = (const float*)d_in[8];
    const float* bm1 = (const float*)d_in[9];
    const float* Wm2 = (const float*)d_in[10];
    const float* bm2 = (const float*)d_in[11];
    float* out = (float*)d_out;

    const int* src = ei;
    const int* dst = ei + N_EDGES;

    char* ws = (char*)d_ws;
    size_t off = 0;
    auto alloc = [&](size_t bytes) { size_t o = off; off = (off + bytes + 255) & ~(size_t)255; return (void*)(ws + o); };
    int*      rowptr = (int*)alloc(4ll * (N_NODES + 1));
    int*      histA  = (int*)alloc(4ll * NHIST);
    int*      baseL  = (int*)alloc(4ll * NHIST);
    int*      bsum   = (int*)alloc(4ll * NHB);
    int*      csr    = (int*)alloc(4ll * (EP + 64));       // +64 pad (zeros)
    float*    dinv   = (float*)alloc(4ll * N_NODES);
    __half*   gfA    = (__half*)alloc(2ll * N_NODES * HID);
    __half*   gfB    = (__half*)alloc(2ll * N_NODES * HID);
    __half*   hvbuf  = (__half*)alloc(2ll * N_NODES * HID);
    unsigned* ebuf   = (unsigned*)alloc(4ll * N_EDGES);
    u64*      obuf   = (u64*)alloc(8ll * (size_t)NBUCK * OBSTRIDE);
    (void)ws_size;

    // --- CSR build v5: 5 dispatches, no memset, no global atomics ---
    hist_kernel<<<NCHUNK, 1024, 0, stream>>>(dst, histA, csr);
    scang_block<<<NHB, 1024, 0, stream>>>(histA, baseL, bsum);
    scang_bsum<<<1, 256, 0, stream>>>(bsum);
    scatter_kernel<<<NCHUNK, 1024, 0, stream>>>(src, dst, baseL, bsum, ebuf);
    rankfill_kernel<<<NBUCK, 256, 0, stream>>>(ebuf, baseL, bsum, obuf, rowptr, csr, dinv);

    // --- layers: gather(+hv) then MFMA transform ---
    const int gblocks = N_NODES / (4 * NPN);   // 6250, exact
    const int fblocks = (NTILE + 3) / 4;       // 1563
    layer1_kernel<<<(N_NODES * HID + 255) / 256, 256, 0, stream>>>(x, W1, dinv, gfA);
    gather_kernel<<<gblocks, 256, 0, stream>>>(gfA, rowptr, csr, dinv, b1, hvbuf);
    mfma_transform_kernel<<<fblocks, 256, 0, stream>>>(hvbuf, dinv, W2, gfB);
    gather_kernel<<<gblocks, 256, 0, stream>>>(gfB, rowptr, csr, dinv, b2, hvbuf);
    mfma_transform_kernel<<<fblocks, 256, 0, stream>>>(hvbuf, dinv, W3, gfA);
    gather_kernel<<<gblocks, 256, 0, stream>>>(gfA, rowptr, csr, dinv, b3, hvbuf);
    mfma_final_kernel<<<fblocks, 256, 0, stream>>>(hvbuf, Wm1, bm1, Wm2, bm2, out);
}

// Round 17
// 241.464 us; speedup vs baseline: 1.0952x; 1.0439x over previous
//
#include <hip/hip_runtime.h>
#include <hip/hip_fp16.h>
#include <math.h>

#define N_NODES 100000
#define N_EDGES 1600000
#define EP (N_EDGES + N_NODES)   // edges incl self-loops
#define HID 64
#define NCHUNK 128                               // hist/scatter chunks
#define CE (N_EDGES / NCHUNK)                    // 12500 edges per chunk (exact)
#define NBUCK 391                                // buckets of 256 node-keys
#define NHIST (NBUCK * NCHUNK)                   // 50048
#define NHB ((NHIST + 1023) / 1024)              // 49 scan blocks
#define NTILE (N_NODES / 16)                     // 6250 tiles = blocks (exact)
#define STASH 8192                               // per-bucket stash (u32)
#define OBSTRIDE 4096                            // u64 overflow slots per bucket
#define NPN 4                                    // nodes per wave (gather), even

typedef _Float16 half8_t __attribute__((ext_vector_type(8)));
typedef _Float16 half4_t __attribute__((ext_vector_type(4)));
typedef float f32x4_t __attribute__((ext_vector_type(4)));
typedef unsigned long long u64;

// ================= bucketed CSR build v5 (R16-proven) =================

__global__ __launch_bounds__(1024)
void hist_kernel(const int* __restrict__ dst, int* __restrict__ histA,
                 int* __restrict__ csr) {
    __shared__ int hist[NBUCK];
    const int tid = threadIdx.x, c = blockIdx.x;
    for (int b = tid; b < NBUCK; b += 1024) hist[b] = 0;
    __syncthreads();
    const int4* d4p = (const int4*)(dst + c * CE);
    for (int t = tid; t < CE / 4; t += 1024) {
        int4 d = d4p[t];
        atomicAdd(&hist[d.x >> 8], 1);
        atomicAdd(&hist[d.y >> 8], 1);
        atomicAdd(&hist[d.z >> 8], 1);
        atomicAdd(&hist[d.w >> 8], 1);
    }
    __syncthreads();
    for (int b = tid; b < NBUCK; b += 1024) histA[b * NCHUNK + c] = hist[b];
    if (c == 0 && tid < 64) csr[EP + tid] = 0;   // zero pad for gather over-read
}

__global__ void scang_block(const int* __restrict__ in, int* __restrict__ baseL,
                            int* __restrict__ bsum) {
    __shared__ int wsum[16];
    int tid = threadIdx.x, lane = tid & 63, wid = tid >> 6;
    int i = blockIdx.x * 1024 + tid;
    int x = (i < NHIST) ? in[i] : 0;
    int inc = x;
#pragma unroll
    for (int off = 1; off < 64; off <<= 1) {
        int y = __shfl_up(inc, off, 64);
        if (lane >= off) inc += y;
    }
    if (lane == 63) wsum[wid] = inc;
    __syncthreads();
    if (tid == 0) {
        int s = 0;
#pragma unroll
        for (int j = 0; j < 16; ++j) { int t2 = wsum[j]; wsum[j] = s; s += t2; }
    }
    __syncthreads();
    if (i < NHIST) baseL[i] = wsum[wid] + inc - x;
    if (tid == 1023) bsum[blockIdx.x] = wsum[15] + inc;
}

__global__ void scang_bsum(int* __restrict__ bsum) {   // NHB <= 256
    __shared__ int tmp[256];
    int t = threadIdx.x;
    tmp[t] = (t < NHB) ? bsum[t] : 0;
    __syncthreads();
    for (int off = 1; off < 256; off <<= 1) {
        int v = (t >= off) ? tmp[t - off] : 0;
        __syncthreads();
        tmp[t] += v;
        __syncthreads();
    }
    if (t < NHB) bsum[t] = (t == 0) ? 0 : tmp[t - 1];
}

__global__ __launch_bounds__(1024)
void scatter_kernel(const int* __restrict__ src, const int* __restrict__ dst,
                    const int* __restrict__ baseL, const int* __restrict__ bsum,
                    unsigned* __restrict__ ebuf) {
    __shared__ int cur[NBUCK];
    const int tid = threadIdx.x, c = blockIdx.x;
    for (int b = tid; b < NBUCK; b += 1024) {
        int idx = b * NCHUNK + c;
        cur[b] = baseL[idx] + bsum[idx >> 10];
    }
    __syncthreads();
    const int4* s4p = (const int4*)(src + c * CE);
    const int4* d4p = (const int4*)(dst + c * CE);
    for (int t = tid; t < CE / 4; t += 1024) {
        int4 s = s4p[t];
        int4 d = d4p[t];
        int p0 = atomicAdd(&cur[d.x >> 8], 1);
        ebuf[p0] = ((unsigned)(d.x & 255) << 17) | (unsigned)s.x;
        int p1 = atomicAdd(&cur[d.y >> 8], 1);
        ebuf[p1] = ((unsigned)(d.y & 255) << 17) | (unsigned)s.y;
        int p2 = atomicAdd(&cur[d.z >> 8], 1);
        ebuf[p2] = ((unsigned)(d.z & 255) << 17) | (unsigned)s.z;
        int p3 = atomicAdd(&cur[d.w >> 8], 1);
        ebuf[p3] = ((unsigned)(d.w & 255) << 17) | (unsigned)s.w;
    }
}

__global__ __launch_bounds__(256)
void rankfill_kernel(const unsigned* __restrict__ ebuf, const int* __restrict__ baseL,
                     const int* __restrict__ bsum, u64* __restrict__ obuf,
                     int* __restrict__ rowptr, int* __restrict__ csr,
                     float* __restrict__ dinv) {
    __shared__ int cnt[256];
    __shared__ int rpl[256];
    __shared__ int wsum[4];
    __shared__ int ocnt;
    __shared__ unsigned stash[STASH];
    const int tid = threadIdx.x, b = blockIdx.x;
    cnt[tid] = 0;
    if (tid == 0) ocnt = 0;
    __syncthreads();
    const int i0 = b * NCHUNK;
    const int R0 = baseL[i0] + bsum[i0 >> 10];
    const int i1 = (b + 1) * NCHUNK;
    const int R1 = (b == NBUCK - 1) ? N_EDGES : (baseL[i1] + bsum[i1 >> 10]);
    const int RL = R1 - R0;
    for (int off = tid; off < RL; off += 256) {
        unsigned v = ebuf[R0 + off];
        int key = (v >> 17) & 0xFF;
        int r = atomicAdd(&cnt[key], 1);
        if (off < STASH && r < 128) {
            stash[off] = ((unsigned)r << 25) | v;
        } else {
            if (off < STASH) stash[off] = 0xFFFFFFFFu;
            int oi = (off >= STASH) ? (off - STASH) : (2048 + atomicAdd(&ocnt, 1));
            obuf[(size_t)b * OBSTRIDE + oi] =
                ((u64)r << 40) | ((u64)key << 32) | (u64)(v & 0x1FFFFu);
        }
    }
    __syncthreads();
    const int lane = tid & 63, w = tid >> 6;
    int x = cnt[tid];
    int inc = x;
#pragma unroll
    for (int off = 1; off < 64; off <<= 1) {
        int y = __shfl_up(inc, off, 64);
        if (lane >= off) inc += y;
    }
    if (lane == 63) wsum[w] = inc;
    __syncthreads();
    int base = 0;
    for (int k = 0; k < 4; ++k) if (k < w) base += wsum[k];
    int pre = base + inc - x;
    const int n = b * 256 + tid;
    const int rpn = R0 + n + pre;
    rpl[tid] = rpn;
    if (n < N_NODES) {
        rowptr[n] = rpn;
        dinv[n] = rsqrtf((float)(x + 1));
        csr[rpn + x] = n;             // self-loop at end of node's list
    }
    if (b == NBUCK - 1 && tid == 0) rowptr[N_NODES] = EP;
    __syncthreads();
    const int lim = (RL < STASH) ? RL : STASH;
    for (int off = tid; off < lim; off += 256) {
        unsigned v = stash[off];
        if (v == 0xFFFFFFFFu) continue;
        csr[rpl[(v >> 17) & 0xFF] + (v >> 25)] = (int)(v & 0x1FFFFu);
    }
    for (int j = tid; j < RL - STASH; j += 256) {       // ≈ never
        u64 pk = obuf[(size_t)b * OBSTRIDE + j];
        csr[rpl[(pk >> 32) & 0xFF] + (int)(pk >> 40)] = (int)(pk & 0x1FFFFu);
    }
    for (int j = tid; j < ocnt; j += 256) {             // ≈ never
        u64 pk = obuf[(size_t)b * OBSTRIDE + 2048 + j];
        csr[rpl[(pk >> 32) & 0xFF] + (int)(pk >> 40)] = (int)(pk & 0x1FFFFu);
    }
}

// ---------------- layer 1: gf = fp16( dinv * (x @ W1) ), [N][64] ----------------

__global__ void layer1_kernel(const float* __restrict__ x, const float* __restrict__ W1,
                              const float* __restrict__ dinv, __half* __restrict__ gf) {
    int idx = blockIdx.x * blockDim.x + threadIdx.x;
    if (idx >= N_NODES * HID) return;
    int n = idx >> 6, c = idx & 63;
    float v = x[n * 3 + 0] * W1[c] + x[n * 3 + 1] * W1[HID + c]
            + x[n * 3 + 2] * W1[2 * HID + c];
    gf[idx] = __float2half(v * dinv[n]);
}

// ================= fused layer: block = 16-node tile; gather (R14 wave shape) =================
// 4 waves x 4 nodes: gather -> hv fp16 into LDS tile; sync; each wave does its
// 16-column slice of the 16x64 transform (2 MFMAs) + block LDS transpose store.

__device__ __forceinline__ void addp(float4& a, uint2 u, bool pred) {
    __half2 h0 = *(__half2*)&u.x, h1 = *(__half2*)&u.y;
    float2 x = __half22float2(h0), y = __half22float2(h1);
    if (pred) { a.x += x.x; a.y += x.y; a.z += y.x; a.w += y.y; }
}

__device__ __forceinline__ void bfly_store_lds(float4 acc, const float4 b4, float di,
                                               int g, int p, int l, _Float16* __restrict__ tl) {
    acc.x += __shfl_xor(acc.x, 16, 64);
    acc.y += __shfl_xor(acc.y, 16, 64);
    acc.z += __shfl_xor(acc.z, 16, 64);
    acc.w += __shfl_xor(acc.w, 16, 64);
    acc.x += __shfl_xor(acc.x, 32, 64);
    acc.y += __shfl_xor(acc.y, 32, 64);
    acc.z += __shfl_xor(acc.z, 32, 64);
    acc.w += __shfl_xor(acc.w, 32, 64);
    if (g == 0) {
        half4_t hv;
        hv[0] = (_Float16)fmaxf(fmaf(di, acc.x, b4.x), 0.f);
        hv[1] = (_Float16)fmaxf(fmaf(di, acc.y, b4.y), 0.f);
        hv[2] = (_Float16)fmaxf(fmaf(di, acc.z, b4.z), 0.f);
        hv[3] = (_Float16)fmaxf(fmaf(di, acc.w, b4.w), 0.f);
        *(half4_t*)(tl + l * 72 + p * 4) = hv;
    }
}

// gather of NPN nodes into LDS tile rows [wid*4 .. wid*4+3]
__device__ __forceinline__ void gather_phase(const __half* __restrict__ gf,
                                             const int* __restrict__ rowptr,
                                             const int* __restrict__ csr,
                                             const float* __restrict__ dinv,
                                             const float* __restrict__ bias,
                                             int n0, int lane, int wid,
                                             _Float16* __restrict__ tl) {
    const int g = lane >> 4, p = lane & 15;
    const int nw = n0 + wid * NPN;
    int rp = rowptr[nw + min(lane, NPN)];
    const uint2* gf2 = (const uint2*)gf;
    const float4 b4 = ((const float4*)bias)[p];
    int begv[NPN], cntv[NPN], idxv[NPN];
    int end_prev = __shfl(rp, 0, 64);
#pragma unroll
    for (int i = 0; i < NPN; ++i) {
        int end = __shfl(rp, i + 1, 64);
        begv[i] = end_prev;
        cntv[i] = end - end_prev;
        end_prev = end;
        idxv[i] = csr[begv[i] + lane];      // safe: csr padded by 64
    }
#pragma unroll
    for (int ii = 0; ii < NPN; ii += 2) {
        const int la = wid * NPN + ii, lb = la + 1;
        const int ca = cntv[ii], cb = cntv[ii + 1];
        const int ba = begv[ii], bb = begv[ii + 1];
        const int iva = idxv[ii], ivb = idxv[ii + 1];
        int sa0 = __shfl(iva, g, 64),      sb0 = __shfl(ivb, g, 64);
        int sa1 = __shfl(iva, g + 4, 64),  sb1 = __shfl(ivb, g + 4, 64);
        int sa2 = __shfl(iva, g + 8, 64),  sb2 = __shfl(ivb, g + 8, 64);
        int sa3 = __shfl(iva, g + 12, 64), sb3 = __shfl(ivb, g + 12, 64);
        uint2 ua0 = gf2[(size_t)sa0 * 16 + p], ub0 = gf2[(size_t)sb0 * 16 + p];
        uint2 ua1 = gf2[(size_t)sa1 * 16 + p], ub1 = gf2[(size_t)sb1 * 16 + p];
        uint2 ua2 = gf2[(size_t)sa2 * 16 + p], ub2 = gf2[(size_t)sb2 * 16 + p];
        uint2 ua3 = gf2[(size_t)sa3 * 16 + p], ub3 = gf2[(size_t)sb3 * 16 + p];
        float4 accA = make_float4(0.f, 0.f, 0.f, 0.f);
        float4 accB = make_float4(0.f, 0.f, 0.f, 0.f);
        addp(accA, ua0, g + 0 < ca);  addp(accB, ub0, g + 0 < cb);
        addp(accA, ua1, g + 4 < ca);  addp(accB, ub1, g + 4 < cb);
        addp(accA, ua2, g + 8 < ca);  addp(accB, ub2, g + 8 < cb);
        addp(accA, ua3, g + 12 < ca); addp(accB, ub3, g + 12 < cb);
        if (ca > 16) {
#pragma unroll
            for (int k = 4; k < 8; ++k) {
                int e = g + 4 * k;
                int s = __shfl(iva, e, 64);
                addp(accA, gf2[(size_t)s * 16 + p], e < ca);
            }
            if (ca > 32) {
                for (int e = 32 + g; e < ca; e += 4) {
                    int s = (e < 64) ? __shfl(iva, e, 64) : csr[ba + e];
                    addp(accA, gf2[(size_t)s * 16 + p], true);
                }
            }
        }
        if (cb > 16) {
#pragma unroll
            for (int k = 4; k < 8; ++k) {
                int e = g + 4 * k;
                int s = __shfl(ivb, e, 64);
                addp(accB, gf2[(size_t)s * 16 + p], e < cb);
            }
            if (cb > 32) {
                for (int e = 32 + g; e < cb; e += 4) {
                    int s = (e < 64) ? __shfl(ivb, e, 64) : csr[bb + e];
                    addp(accB, gf2[(size_t)s * 16 + p], true);
                }
            }
        }
        bfly_store_lds(accA, b4, dinv[n0 + la], g, p, la, tl);
        bfly_store_lds(accB, b4, dinv[n0 + lb], g, p, lb, tl);
    }
}

__global__ __launch_bounds__(256, 8)
void fused_layer_kernel(const __half* __restrict__ gf_in, const int* __restrict__ rowptr,
                        const int* __restrict__ csr, const float* __restrict__ dinv,
                        const float* __restrict__ bias, const float* __restrict__ W,
                        __half* __restrict__ gf_out) {
    __shared__ __align__(16) _Float16 tile[16 * 72];
    __shared__ __align__(16) _Float16 tile2[16 * 72];
    const int tid = threadIdx.x;
    const int lane = tid & 63, wid = tid >> 6;
    const int n0 = blockIdx.x * 16;

    gather_phase(gf_in, rowptr, csr, dinv, bias, n0, lane, wid, tile);
    __syncthreads();

    // wave wid: columns wid*16 + n
    const int kg = lane >> 4, n = lane & 15;
    half8_t B0, B1;
#pragma unroll
    for (int j = 0; j < 8; ++j) {
        B0[j] = (_Float16)W[(kg * 8 + j) * HID + wid * 16 + n];
        B1[j] = (_Float16)W[(32 + kg * 8 + j) * HID + wid * 16 + n];
    }
    half8_t A0 = *(const half8_t*)(tile + n * 72 + kg * 8);
    half8_t A1 = *(const half8_t*)(tile + n * 72 + 32 + kg * 8);
    f32x4_t c = {0.f, 0.f, 0.f, 0.f};
    c = __builtin_amdgcn_mfma_f32_16x16x32_f16(A0, B0, c, 0, 0, 0);
    c = __builtin_amdgcn_mfma_f32_16x16x32_f16(A1, B1, c, 0, 0, 0);

    // epilogue: scale by di[row], write to tile2 (block transpose), coalesced store
    const int q = lane >> 4;
#pragma unroll
    for (int r = 0; r < 4; ++r)
        tile2[(q * 4 + r) * 72 + wid * 16 + n] = (_Float16)(c[r] * dinv[n0 + q * 4 + r]);
    __syncthreads();
    const int row = tid >> 4, seg = tid & 15;
    uint2 v = *(const uint2*)(tile2 + row * 72 + seg * 4);
    *(uint2*)((__half*)gf_out + (size_t)(n0 + row) * HID + seg * 4) = v;
}

// ================= fused final: gather -> hv LDS -> MFMA(Wm1) + head + sigmoid =================

__global__ __launch_bounds__(256, 8)
void fused_final_kernel(const __half* __restrict__ gf_in, const int* __restrict__ rowptr,
                        const int* __restrict__ csr, const float* __restrict__ dinv,
                        const float* __restrict__ b3, const float* __restrict__ Wm1,
                        const float* __restrict__ bm1, const float* __restrict__ Wm2,
                        const float* __restrict__ bm2, float* __restrict__ out) {
    __shared__ __align__(16) _Float16 tile[16 * 72];
    __shared__ float redbuf[4][16];
    const int tid = threadIdx.x;
    const int lane = tid & 63, wid = tid >> 6;
    const int n0 = blockIdx.x * 16;

    gather_phase(gf_in, rowptr, csr, dinv, b3, n0, lane, wid, tile);
    __syncthreads();

    const int kg = lane >> 4, n = lane & 15;
    half8_t B0, B1;
#pragma unroll
    for (int j = 0; j < 8; ++j) {
        B0[j] = (_Float16)Wm1[(kg * 8 + j) * HID + wid * 16 + n];
        B1[j] = (_Float16)Wm1[(32 + kg * 8 + j) * HID + wid * 16 + n];
    }
    half8_t A0 = *(const half8_t*)(tile + n * 72 + kg * 8);
    half8_t A1 = *(const half8_t*)(tile + n * 72 + 32 + kg * 8);
    f32x4_t c = {0.f, 0.f, 0.f, 0.f};
    c = __builtin_amdgcn_mfma_f32_16x16x32_f16(A0, B0, c, 0, 0, 0);
    c = __builtin_amdgcn_mfma_f32_16x16x32_f16(A1, B1, c, 0, 0, 0);

    // head: this lane holds column wid*16+n, rows q*4+r
    const float bm1c = bm1[wid * 16 + n];
    const float wm2c = Wm2[wid * 16 + n];
    float part[4];
#pragma unroll
    for (int r = 0; r < 4; ++r) part[r] = fmaxf(c[r] + bm1c, 0.0f) * wm2c;
#pragma unroll
    for (int off = 1; off < 16; off <<= 1)
#pragma unroll
        for (int r = 0; r < 4; ++r) part[r] += __shfl_xor(part[r], off, 64);
    const int q = lane >> 4;
    if (n == 0) {
#pragma unroll
        for (int r = 0; r < 4; ++r) redbuf[wid][q * 4 + r] = part[r];
    }
    __syncthreads();
    if (tid < 16) {
        float s = redbuf[0][tid] + redbuf[1][tid] + redbuf[2][tid] + redbuf[3][tid];
        out[n0 + tid] = 1.0f / (1.0f + expf(-(s + bm2[0])));
    }
}

// ---------------- launch ----------------

extern "C" void kernel_launch(void* const* d_in, const int* in_sizes, int n_in,
                              void* d_out, int out_size, void* d_ws, size_t ws_size,
                              hipStream_t stream) {
    const float* x   = (const float*)d_in[0];
    const int*   ei  = (const int*)d_in[1];
    const float* W1  = (const float*)d_in[2];
    const float* b1  = (const float*)d_in[3];
    const float* W2  = (const float*)d_in[4];
    const float* b2  = (const float*)d_in[5];
    const float* W3  = (const float*)d_in[6];
    const float* b3  = (const float*)d_in[7];
    const float* Wm1 = (const float*)d_in[8];
    const float* bm1 = (const float*)d_in[9];
    const float* Wm2 = (const float*)d_in[10];
    const float* bm2 = (const float*)d_in[11];
    float* out = (float*)d_out;

    const int* src = ei;
    const int* dst = ei + N_EDGES;

    char* ws = (char*)d_ws;
    size_t off = 0;
    auto alloc = [&](size_t bytes) { size_t o = off; off = (off + bytes + 255) & ~(size_t)255; return (void*)(ws + o); };
    int*      rowptr = (int*)alloc(4ll * (N_NODES + 1));
    int*      histA  = (int*)alloc(4ll * NHIST);
    int*      baseL  = (int*)alloc(4ll * NHIST);
    int*      bsum   = (int*)alloc(4ll * NHB);
    int*      csr    = (int*)alloc(4ll * (EP + 64));       // +64 pad (zeros)
    float*    dinv   = (float*)alloc(4ll * N_NODES);
    __half*   gfA    = (__half*)alloc(2ll * N_NODES * HID);
    __half*   gfB    = (__half*)alloc(2ll * N_NODES * HID);
    unsigned* ebuf   = (unsigned*)alloc(4ll * N_EDGES);
    u64*      obuf   = (u64*)alloc(8ll * (size_t)NBUCK * OBSTRIDE);
    (void)ws_size;

    // --- CSR build v5: 5 dispatches, no memset, no global atomics ---
    hist_kernel<<<NCHUNK, 1024, 0, stream>>>(dst, histA, csr);
    scang_block<<<NHB, 1024, 0, stream>>>(histA, baseL, bsum);
    scang_bsum<<<1, 256, 0, stream>>>(bsum);
    scatter_kernel<<<NCHUNK, 1024, 0, stream>>>(src, dst, baseL, bsum, ebuf);
    rankfill_kernel<<<NBUCK, 256, 0, stream>>>(ebuf, baseL, bsum, obuf, rowptr, csr, dinv);

    // --- layers: fused gather + MFMA transform (one block = one 16-node tile) ---
    layer1_kernel<<<(N_NODES * HID + 255) / 256, 256, 0, stream>>>(x, W1, dinv, gfA);
    fused_layer_kernel<<<NTILE, 256, 0, stream>>>(gfA, rowptr, csr, dinv, b1, W2, gfB);
    fused_layer_kernel<<<NTILE, 256, 0, stream>>>(gfB, rowptr, csr, dinv, b2, W3, gfA);
    fused_final_kernel<<<NTILE, 256, 0, stream>>>(gfA, rowptr, csr, dinv, b3, Wm1, bm1, Wm2, bm2, out);
}

// Round 18
// 241.361 us; speedup vs baseline: 1.0957x; 1.0004x over previous
//
#include <hip/hip_runtime.h>
#include <hip/hip_fp16.h>
#include <math.h>

#define N_NODES 100000
#define N_EDGES 1600000
#define EP (N_EDGES + N_NODES)   // edges incl self-loops
#define HID 64
#define NCHUNK 128                               // scatter chunks
#define CE (N_EDGES / NCHUNK)                    // 12500 edges per chunk (exact)
#define NBUCK 391                                // buckets of 256 node-keys
#define CAP 5120                                 // fixed ebuf window per bucket (mean 4096, 16 sigma)
#define NTILE (N_NODES / 16)                     // 6250 tiles = blocks (exact)
#define STASH 8192                               // per-bucket stash (u32)
#define OBSTRIDE 4096                            // u64 overflow slots per bucket
#define NPN 4                                    // nodes per wave (gather), even

typedef _Float16 half8_t __attribute__((ext_vector_type(8)));
typedef _Float16 half4_t __attribute__((ext_vector_type(4)));
typedef float f32x4_t __attribute__((ext_vector_type(4)));
typedef unsigned long long u64;

// ================= bucketed CSR build v6 (fixed-capacity, no hist/scan stage) =================

// init: gcur[b] = window start; zero csr pad

__global__ void init_kernel(int* __restrict__ gcur, int* __restrict__ csr) {
    int t = threadIdx.x;
    for (int b = t; b < NBUCK; b += 512) gcur[b] = b * CAP;
    if (t < 64) csr[EP + t] = 0;
}

// scatter: per-block LDS hist -> one global reserve per (block,bucket) -> packed scatter

__global__ __launch_bounds__(1024)
void scatter_kernel(const int* __restrict__ src, const int* __restrict__ dst,
                    int* __restrict__ gcur, unsigned* __restrict__ ebuf) {
    __shared__ int hist[NBUCK];
    __shared__ int cur[NBUCK];
    const int tid = threadIdx.x, c = blockIdx.x;
    for (int b = tid; b < NBUCK; b += 1024) hist[b] = 0;
    __syncthreads();
    const int4* d4p = (const int4*)(dst + c * CE);
    const int4* s4p = (const int4*)(src + c * CE);
    for (int t = tid; t < CE / 4; t += 1024) {
        int4 d = d4p[t];
        atomicAdd(&hist[d.x >> 8], 1);
        atomicAdd(&hist[d.y >> 8], 1);
        atomicAdd(&hist[d.z >> 8], 1);
        atomicAdd(&hist[d.w >> 8], 1);
    }
    __syncthreads();
    for (int b = tid; b < NBUCK; b += 1024)
        cur[b] = hist[b] ? atomicAdd(&gcur[b], hist[b]) : 0;
    __syncthreads();
    for (int t = tid; t < CE / 4; t += 1024) {
        int4 s = s4p[t];
        int4 d = d4p[t];
        int p0 = atomicAdd(&cur[d.x >> 8], 1);
        ebuf[p0] = ((unsigned)(d.x & 255) << 17) | (unsigned)s.x;   // src < 2^17
        int p1 = atomicAdd(&cur[d.y >> 8], 1);
        ebuf[p1] = ((unsigned)(d.y & 255) << 17) | (unsigned)s.y;
        int p2 = atomicAdd(&cur[d.z >> 8], 1);
        ebuf[p2] = ((unsigned)(d.z & 255) << 17) | (unsigned)s.z;
        int p3 = atomicAdd(&cur[d.w >> 8], 1);
        ebuf[p3] = ((unsigned)(d.w & 255) << 17) | (unsigned)s.w;
    }
}

// bscan: exclusive scan of (bucket edge count + 256 self-loops) -> bucket rowptr base

__global__ void bscan_kernel(const int* __restrict__ gcur, int* __restrict__ bR0) {
    __shared__ int tmp[512];
    int t = threadIdx.x;
    int v = (t < NBUCK) ? (gcur[t] - t * CAP + 256) : 0;
    tmp[t] = v;
    __syncthreads();
    for (int off = 1; off < 512; off <<= 1) {
        int y = (t >= off) ? tmp[t - off] : 0;
        __syncthreads();
        tmp[t] += y;
        __syncthreads();
    }
    if (t < NBUCK) bR0[t] = tmp[t] - v;   // exclusive prefix
}

// rankfill: per-bucket rank; cnt scan -> rowptr/dinv/self-loop; csr fill

__global__ __launch_bounds__(256)
void rankfill_kernel(const unsigned* __restrict__ ebuf, const int* __restrict__ gcur,
                     const int* __restrict__ bR0, u64* __restrict__ obuf,
                     int* __restrict__ rowptr, int* __restrict__ csr,
                     float* __restrict__ dinv) {
    __shared__ int cnt[256];
    __shared__ int rpl[256];
    __shared__ int wsum[4];
    __shared__ int ocnt;
    __shared__ unsigned stash[STASH];
    const int tid = threadIdx.x, b = blockIdx.x;
    cnt[tid] = 0;
    if (tid == 0) ocnt = 0;
    __syncthreads();
    const int E0 = b * CAP;
    const int RL = gcur[b] - E0;          // bucket edge count
    const int R0 = bR0[b];                // global rowptr base for this bucket
    for (int off = tid; off < RL; off += 256) {
        unsigned v = ebuf[E0 + off];
        int key = (v >> 17) & 0xFF;
        int r = atomicAdd(&cnt[key], 1);
        if (off < STASH && r < 128) {
            stash[off] = ((unsigned)r << 25) | v;
        } else {
            if (off < STASH) stash[off] = 0xFFFFFFFFu;
            int oi = (off >= STASH) ? (off - STASH) : (2048 + atomicAdd(&ocnt, 1));
            obuf[(size_t)b * OBSTRIDE + oi] =
                ((u64)r << 40) | ((u64)key << 32) | (u64)(v & 0x1FFFFu);
        }
    }
    __syncthreads();
    const int lane = tid & 63, w = tid >> 6;
    int x = cnt[tid];
    int inc = x;
#pragma unroll
    for (int off = 1; off < 64; off <<= 1) {
        int y = __shfl_up(inc, off, 64);
        if (lane >= off) inc += y;
    }
    if (lane == 63) wsum[w] = inc;
    __syncthreads();
    int base = 0;
    for (int k = 0; k < 4; ++k) if (k < w) base += wsum[k];
    int pre = base + inc - x;
    const int n = b * 256 + tid;
    const int rpn = R0 + tid + pre;       // bucket base + in-bucket self-loops + edge prefix
    rpl[tid] = rpn;
    if (n < N_NODES) {
        rowptr[n] = rpn;
        dinv[n] = rsqrtf((float)(x + 1));
        csr[rpn + x] = n;                 // self-loop at end of node's list
    }
    if (b == NBUCK - 1 && tid == 0) rowptr[N_NODES] = EP;
    __syncthreads();
    const int lim = (RL < STASH) ? RL : STASH;
    for (int off = tid; off < lim; off += 256) {
        unsigned v = stash[off];
        if (v == 0xFFFFFFFFu) continue;
        csr[rpl[(v >> 17) & 0xFF] + (v >> 25)] = (int)(v & 0x1FFFFu);
    }
    for (int j = tid; j < RL - STASH; j += 256) {       // ≈ never
        u64 pk = obuf[(size_t)b * OBSTRIDE + j];
        csr[rpl[(pk >> 32) & 0xFF] + (int)(pk >> 40)] = (int)(pk & 0x1FFFFu);
    }
    for (int j = tid; j < ocnt; j += 256) {             // ≈ never
        u64 pk = obuf[(size_t)b * OBSTRIDE + 2048 + j];
        csr[rpl[(pk >> 32) & 0xFF] + (int)(pk >> 40)] = (int)(pk & 0x1FFFFu);
    }
}

// ---------------- layer 1: gf = fp16( dinv * (x @ W1) ), [N][64] ----------------

__global__ void layer1_kernel(const float* __restrict__ x, const float* __restrict__ W1,
                              const float* __restrict__ dinv, __half* __restrict__ gf) {
    int idx = blockIdx.x * blockDim.x + threadIdx.x;
    if (idx >= N_NODES * HID) return;
    int n = idx >> 6, c = idx & 63;
    float v = x[n * 3 + 0] * W1[c] + x[n * 3 + 1] * W1[HID + c]
            + x[n * 3 + 2] * W1[2 * HID + c];
    gf[idx] = __float2half(v * dinv[n]);
}

// ================= fused layer (R17-proven): block = 16-node tile =================

__device__ __forceinline__ void addp(float4& a, uint2 u, bool pred) {
    __half2 h0 = *(__half2*)&u.x, h1 = *(__half2*)&u.y;
    float2 x = __half22float2(h0), y = __half22float2(h1);
    if (pred) { a.x += x.x; a.y += x.y; a.z += y.x; a.w += y.y; }
}

__device__ __forceinline__ void bfly_store_lds(float4 acc, const float4 b4, float di,
                                               int g, int p, int l, _Float16* __restrict__ tl) {
    acc.x += __shfl_xor(acc.x, 16, 64);
    acc.y += __shfl_xor(acc.y, 16, 64);
    acc.z += __shfl_xor(acc.z, 16, 64);
    acc.w += __shfl_xor(acc.w, 16, 64);
    acc.x += __shfl_xor(acc.x, 32, 64);
    acc.y += __shfl_xor(acc.y, 32, 64);
    acc.z += __shfl_xor(acc.z, 32, 64);
    acc.w += __shfl_xor(acc.w, 32, 64);
    if (g == 0) {
        half4_t hv;
        hv[0] = (_Float16)fmaxf(fmaf(di, acc.x, b4.x), 0.f);
        hv[1] = (_Float16)fmaxf(fmaf(di, acc.y, b4.y), 0.f);
        hv[2] = (_Float16)fmaxf(fmaf(di, acc.z, b4.z), 0.f);
        hv[3] = (_Float16)fmaxf(fmaf(di, acc.w, b4.w), 0.f);
        *(half4_t*)(tl + l * 72 + p * 4) = hv;
    }
}

__device__ __forceinline__ void gather_phase(const __half* __restrict__ gf,
                                             const int* __restrict__ rowptr,
                                             const int* __restrict__ csr,
                                             const float* __restrict__ dinv,
                                             const float* __restrict__ bias,
                                             int n0, int lane, int wid,
                                             _Float16* __restrict__ tl) {
    const int g = lane >> 4, p = lane & 15;
    const int nw = n0 + wid * NPN;
    int rp = rowptr[nw + min(lane, NPN)];
    const uint2* gf2 = (const uint2*)gf;
    const float4 b4 = ((const float4*)bias)[p];
    int begv[NPN], cntv[NPN], idxv[NPN];
    int end_prev = __shfl(rp, 0, 64);
#pragma unroll
    for (int i = 0; i < NPN; ++i) {
        int end = __shfl(rp, i + 1, 64);
        begv[i] = end_prev;
        cntv[i] = end - end_prev;
        end_prev = end;
        // predicated: masked lanes skip -> fewer 64B segments fetched
        idxv[i] = (lane < cntv[i]) ? csr[begv[i] + lane] : 0;
    }
#pragma unroll
    for (int ii = 0; ii < NPN; ii += 2) {
        const int la = wid * NPN + ii, lb = la + 1;
        const int ca = cntv[ii], cb = cntv[ii + 1];
        const int ba = begv[ii], bb = begv[ii + 1];
        const int iva = idxv[ii], ivb = idxv[ii + 1];
        int sa0 = __shfl(iva, g, 64),      sb0 = __shfl(ivb, g, 64);
        int sa1 = __shfl(iva, g + 4, 64),  sb1 = __shfl(ivb, g + 4, 64);
        int sa2 = __shfl(iva, g + 8, 64),  sb2 = __shfl(ivb, g + 8, 64);
        int sa3 = __shfl(iva, g + 12, 64), sb3 = __shfl(ivb, g + 12, 64);
        uint2 ua0 = gf2[(size_t)sa0 * 16 + p], ub0 = gf2[(size_t)sb0 * 16 + p];
        uint2 ua1 = gf2[(size_t)sa1 * 16 + p], ub1 = gf2[(size_t)sb1 * 16 + p];
        uint2 ua2 = gf2[(size_t)sa2 * 16 + p], ub2 = gf2[(size_t)sb2 * 16 + p];
        uint2 ua3 = gf2[(size_t)sa3 * 16 + p], ub3 = gf2[(size_t)sb3 * 16 + p];
        float4 accA = make_float4(0.f, 0.f, 0.f, 0.f);
        float4 accB = make_float4(0.f, 0.f, 0.f, 0.f);
        addp(accA, ua0, g + 0 < ca);  addp(accB, ub0, g + 0 < cb);
        addp(accA, ua1, g + 4 < ca);  addp(accB, ub1, g + 4 < cb);
        addp(accA, ua2, g + 8 < ca);  addp(accB, ub2, g + 8 < cb);
        addp(accA, ua3, g + 12 < ca); addp(accB, ub3, g + 12 < cb);
        if (ca > 16) {
#pragma unroll
            for (int k = 4; k < 8; ++k) {
                int e = g + 4 * k;
                int s = __shfl(iva, e, 64);
                addp(accA, gf2[(size_t)s * 16 + p], e < ca);
            }
            if (ca > 32) {
                for (int e = 32 + g; e < ca; e += 4) {
                    int s = (e < 64) ? __shfl(iva, e, 64) : csr[ba + e];
                    addp(accA, gf2[(size_t)s * 16 + p], true);
                }
            }
        }
        if (cb > 16) {
#pragma unroll
            for (int k = 4; k < 8; ++k) {
                int e = g + 4 * k;
                int s = __shfl(ivb, e, 64);
                addp(accB, gf2[(size_t)s * 16 + p], e < cb);
            }
            if (cb > 32) {
                for (int e = 32 + g; e < cb; e += 4) {
                    int s = (e < 64) ? __shfl(ivb, e, 64) : csr[bb + e];
                    addp(accB, gf2[(size_t)s * 16 + p], true);
                }
            }
        }
        bfly_store_lds(accA, b4, dinv[n0 + la], g, p, la, tl);
        bfly_store_lds(accB, b4, dinv[n0 + lb], g, p, lb, tl);
    }
}

__global__ __launch_bounds__(256, 8)
void fused_layer_kernel(const __half* __restrict__ gf_in, const int* __restrict__ rowptr,
                        const int* __restrict__ csr, const float* __restrict__ dinv,
                        const float* __restrict__ bias, const float* __restrict__ W,
                        __half* __restrict__ gf_out) {
    __shared__ __align__(16) _Float16 tile[16 * 72];
    __shared__ __align__(16) _Float16 tile2[16 * 72];
    const int tid = threadIdx.x;
    const int lane = tid & 63, wid = tid >> 6;
    const int n0 = blockIdx.x * 16;

    gather_phase(gf_in, rowptr, csr, dinv, bias, n0, lane, wid, tile);
    __syncthreads();

    const int kg = lane >> 4, n = lane & 15;
    half8_t B0, B1;
#pragma unroll
    for (int j = 0; j < 8; ++j) {
        B0[j] = (_Float16)W[(kg * 8 + j) * HID + wid * 16 + n];
        B1[j] = (_Float16)W[(32 + kg * 8 + j) * HID + wid * 16 + n];
    }
    half8_t A0 = *(const half8_t*)(tile + n * 72 + kg * 8);
    half8_t A1 = *(const half8_t*)(tile + n * 72 + 32 + kg * 8);
    f32x4_t c = {0.f, 0.f, 0.f, 0.f};
    c = __builtin_amdgcn_mfma_f32_16x16x32_f16(A0, B0, c, 0, 0, 0);
    c = __builtin_amdgcn_mfma_f32_16x16x32_f16(A1, B1, c, 0, 0, 0);

    const int q = lane >> 4;
#pragma unroll
    for (int r = 0; r < 4; ++r)
        tile2[(q * 4 + r) * 72 + wid * 16 + n] = (_Float16)(c[r] * dinv[n0 + q * 4 + r]);
    __syncthreads();
    const int row = tid >> 4, seg = tid & 15;
    uint2 v = *(const uint2*)(tile2 + row * 72 + seg * 4);
    *(uint2*)((__half*)gf_out + (size_t)(n0 + row) * HID + seg * 4) = v;
}

// ================= fused final: gather -> hv LDS -> MFMA(Wm1) + head + sigmoid =================

__global__ __launch_bounds__(256, 8)
void fused_final_kernel(const __half* __restrict__ gf_in, const int* __restrict__ rowptr,
                        const int* __restrict__ csr, const float* __restrict__ dinv,
                        const float* __restrict__ b3, const float* __restrict__ Wm1,
                        const float* __restrict__ bm1, const float* __restrict__ Wm2,
                        const float* __restrict__ bm2, float* __restrict__ out) {
    __shared__ __align__(16) _Float16 tile[16 * 72];
    __shared__ float redbuf[4][16];
    const int tid = threadIdx.x;
    const int lane = tid & 63, wid = tid >> 6;
    const int n0 = blockIdx.x * 16;

    gather_phase(gf_in, rowptr, csr, dinv, b3, n0, lane, wid, tile);
    __syncthreads();

    const int kg = lane >> 4, n = lane & 15;
    half8_t B0, B1;
#pragma unroll
    for (int j = 0; j < 8; ++j) {
        B0[j] = (_Float16)Wm1[(kg * 8 + j) * HID + wid * 16 + n];
        B1[j] = (_Float16)Wm1[(32 + kg * 8 + j) * HID + wid * 16 + n];
    }
    half8_t A0 = *(const half8_t*)(tile + n * 72 + kg * 8);
    half8_t A1 = *(const half8_t*)(tile + n * 72 + 32 + kg * 8);
    f32x4_t c = {0.f, 0.f, 0.f, 0.f};
    c = __builtin_amdgcn_mfma_f32_16x16x32_f16(A0, B0, c, 0, 0, 0);
    c = __builtin_amdgcn_mfma_f32_16x16x32_f16(A1, B1, c, 0, 0, 0);

    const float bm1c = bm1[wid * 16 + n];
    const float wm2c = Wm2[wid * 16 + n];
    float part[4];
#pragma unroll
    for (int r = 0; r < 4; ++r) part[r] = fmaxf(c[r] + bm1c, 0.0f) * wm2c;
#pragma unroll
    for (int off = 1; off < 16; off <<= 1)
#pragma unroll
        for (int r = 0; r < 4; ++r) part[r] += __shfl_xor(part[r], off, 64);
    const int q = lane >> 4;
    if (n == 0) {
#pragma unroll
        for (int r = 0; r < 4; ++r) redbuf[wid][q * 4 + r] = part[r];
    }
    __syncthreads();
    if (tid < 16) {
        float s = redbuf[0][tid] + redbuf[1][tid] + redbuf[2][tid] + redbuf[3][tid];
        out[n0 + tid] = 1.0f / (1.0f + expf(-(s + bm2[0])));
    }
}

// ---------------- launch ----------------

extern "C" void kernel_launch(void* const* d_in, const int* in_sizes, int n_in,
                              void* d_out, int out_size, void* d_ws, size_t ws_size,
                              hipStream_t stream) {
    const float* x   = (const float*)d_in[0];
    const int*   ei  = (const int*)d_in[1];
    const float* W1  = (const float*)d_in[2];
    const float* b1  = (const float*)d_in[3];
    const float* W2  = (const float*)d_in[4];
    const float* b2  = (const float*)d_in[5];
    const float* W3  = (const float*)d_in[6];
    const float* b3  = (const float*)d_in[7];
    const float* Wm1 = (const float*)d_in[8];
    const float* bm1 = (const float*)d_in[9];
    const float* Wm2 = (const float*)d_in[10];
    const float* bm2 = (const float*)d_in[11];
    float* out = (float*)d_out;

    const int* src = ei;
    const int* dst = ei + N_EDGES;

    char* ws = (char*)d_ws;
    size_t off = 0;
    auto alloc = [&](size_t bytes) { size_t o = off; off = (off + bytes + 255) & ~(size_t)255; return (void*)(ws + o); };
    int*      rowptr = (int*)alloc(4ll * (N_NODES + 1));
    int*      gcur   = (int*)alloc(4ll * NBUCK);
    int*      bR0    = (int*)alloc(4ll * NBUCK);
    int*      csr    = (int*)alloc(4ll * (EP + 64));       // +64 pad (zeros)
    float*    dinv   = (float*)alloc(4ll * N_NODES);
    __half*   gfA    = (__half*)alloc(2ll * N_NODES * HID);
    __half*   gfB    = (__half*)alloc(2ll * N_NODES * HID);
    unsigned* ebuf   = (unsigned*)alloc(4ll * (size_t)NBUCK * CAP);
    u64*      obuf   = (u64*)alloc(8ll * (size_t)NBUCK * OBSTRIDE);
    (void)ws_size;

    // --- CSR build v6: 4 dispatches, fixed-capacity buckets ---
    init_kernel<<<1, 512, 0, stream>>>(gcur, csr);
    scatter_kernel<<<NCHUNK, 1024, 0, stream>>>(src, dst, gcur, ebuf);
    bscan_kernel<<<1, 512, 0, stream>>>(gcur, bR0);
    rankfill_kernel<<<NBUCK, 256, 0, stream>>>(ebuf, gcur, bR0, obuf, rowptr, csr, dinv);

    // --- layers: fused gather + MFMA transform (one block = one 16-node tile) ---
    layer1_kernel<<<(N_NODES * HID + 255) / 256, 256, 0, stream>>>(x, W1, dinv, gfA);
    fused_layer_kernel<<<NTILE, 256, 0, stream>>>(gfA, rowptr, csr, dinv, b1, W2, gfB);
    fused_layer_kernel<<<NTILE, 256, 0, stream>>>(gfB, rowptr, csr, dinv, b2, W3, gfA);
    fused_final_kernel<<<NTILE, 256, 0, stream>>>(gfA, rowptr, csr, dinv, b3, Wm1, bm1, Wm2, bm2, out);
}